// Round 8
// baseline (239.806 us; speedup 1.0000x reference)
//
#include <hip/hip_runtime.h>
#include <math.h>

#define NN 100000
#define NE 1600000
#define HID 64
#define OUTC 32
#define NEG 0.2f
#define NBUCK 196      // ceil(100000/512) buckets of 512 dst nodes
#define EPB 8000       // edges per partition block
#define NPB 200        // NE / EPB partition blocks

typedef float f32x2 __attribute__((ext_vector_type(2)));

__device__ __forceinline__ f32x2 pk_add(f32x2 a, f32x2 b) {
    f32x2 r;
    asm("v_pk_add_f32 %0, %1, %2" : "=v"(r) : "v"(a), "v"(b));
    return r;
}
__device__ __forceinline__ f32x2 pk_mul(f32x2 a, f32x2 b) {
    f32x2 r;
    asm("v_pk_mul_f32 %0, %1, %2" : "=v"(r) : "v"(a), "v"(b));
    return r;
}
__device__ __forceinline__ f32x2 pk_fma(f32x2 a, f32x2 b, f32x2 c) {
    f32x2 r;
    asm("v_pk_fma_f32 %0, %1, %2, %3" : "=v"(r) : "v"(a), "v"(b), "v"(c));
    return r;
}
__device__ __forceinline__ f32x2 pk_abs(f32x2 a) {
    f32x2 r;
    r.x = __builtin_fabsf(a.x);
    r.y = __builtin_fabsf(a.y);
    return r;
}

// ---------- CSR build: 2-level bucket sort ----------

__global__ __launch_bounds__(256) void bucketA_kernel(const int* __restrict__ ei,
                                                      int* __restrict__ gcount,
                                                      int* __restrict__ blkcnt) {
    __shared__ int cnt[NBUCK];
    int tid = threadIdx.x;
    for (int i = tid; i < NBUCK; i += 256) cnt[i] = 0;
    __syncthreads();
    int base = blockIdx.x * EPB;
    const int* dstp = ei + NE;
    for (int i = tid; i < EPB; i += 256) atomicAdd(&cnt[dstp[base + i] >> 9], 1);
    __syncthreads();
    for (int i = tid; i < NBUCK; i += 256) {
        blkcnt[i * NPB + blockIdx.x] = cnt[i];
        atomicAdd(&gcount[i], cnt[i]);
    }
}

__global__ __launch_bounds__(256) void scanBlk_kernel(const int* __restrict__ gcount,
                                                      const int* __restrict__ blkcnt,
                                                      int* __restrict__ cursors,
                                                      int* __restrict__ gbase_arr) {
    __shared__ int sbuf[256];
    __shared__ int swave[4];
    int b = blockIdx.x;
    int tid = threadIdx.x;
    int gv = (tid < b) ? gcount[tid] : 0;
    for (int off = 1; off < 64; off <<= 1) gv += __shfl_xor(gv, off);
    if ((tid & 63) == 0) swave[tid >> 6] = gv;
    __syncthreads();
    int gbase = swave[0] + swave[1] + swave[2] + swave[3];
    int v = (tid < NPB) ? blkcnt[b * NPB + tid] : 0;
    int run = v;
    sbuf[tid] = run;
    __syncthreads();
    for (int off = 1; off < 256; off <<= 1) {
        int u = (tid >= off) ? sbuf[tid - off] : 0;
        __syncthreads();
        run += u;
        sbuf[tid] = run;
        __syncthreads();
    }
    if (tid < NPB) cursors[b * NPB + tid] = gbase + run - v;
    if (tid == 0) {
        gbase_arr[b] = gbase;
        if (b == 0) gbase_arr[NBUCK] = NE;
    }
}

__global__ __launch_bounds__(256) void bucketB_kernel(const int* __restrict__ ei,
                                                      const int* __restrict__ cursors,
                                                      unsigned int* __restrict__ staging) {
    __shared__ int cur[NBUCK];
    int tid = threadIdx.x;
    for (int i = tid; i < NBUCK; i += 256) cur[i] = cursors[i * NPB + blockIdx.x];
    __syncthreads();
    int base = blockIdx.x * EPB;
    const int* dstp = ei + NE;
    for (int i = tid; i < EPB; i += 256) {
        int d = dstp[base + i];
        int s = ei[base + i];
        int pos = atomicAdd(&cur[d >> 9], 1);
        staging[pos] = ((unsigned int)(d & 511) << 17) | (unsigned int)s;
    }
}

__global__ __launch_bounds__(256) void bucketC_kernel(const unsigned int* __restrict__ staging,
                                                      const int* __restrict__ gbase,
                                                      int* __restrict__ rowptr,
                                                      int* __restrict__ csr_src) {
    int b = blockIdx.x;
    int node0 = b << 9;
    int nnode = min(512, NN - node0);
    int e0 = gbase[b], e1 = gbase[b + 1];
    __shared__ int deg[512];
    __shared__ int sbuf[256];
    int tid = threadIdx.x;
    deg[tid] = 0;
    deg[tid + 256] = 0;
    __syncthreads();
    for (int e = e0 + tid; e < e1; e += 256) atomicAdd(&deg[staging[e] >> 17], 1);
    __syncthreads();
    int d0 = deg[2 * tid], d1 = deg[2 * tid + 1];
    int tsum = d0 + d1;
    int run = tsum;
    sbuf[tid] = tsum;
    __syncthreads();
    for (int off = 1; off < 256; off <<= 1) {
        int u = (tid >= off) ? sbuf[tid - off] : 0;
        __syncthreads();
        run += u;
        sbuf[tid] = run;
        __syncthreads();
    }
    int eb = run - tsum;
    deg[2 * tid] = eb;
    deg[2 * tid + 1] = eb + d0;
    if (2 * tid < nnode) rowptr[node0 + 2 * tid] = e0 + eb;
    if (2 * tid + 1 < nnode) rowptr[node0 + 2 * tid + 1] = e0 + eb + d0;
    if (b == NBUCK - 1 && tid == 0) rowptr[NN] = NE;
    __syncthreads();
    for (int e = e0 + tid; e < e1; e += 256) {
        unsigned int p = staging[e];
        int dl = p >> 17;
        int src = (int)(p & 0x1FFFFu);
        int pos = e0 + atomicAdd(&deg[dl], 1);
        csr_src[pos] = src;
    }
}

// ---------- layer 1 ----------

__global__ __launch_bounds__(256) void lin1_kernel(const float* __restrict__ x,
                                                   const float* __restrict__ Wl,
                                                   float* __restrict__ xl) {
    __shared__ float sWl[4 * HID];
    for (int i = threadIdx.x; i < 4 * HID; i += blockDim.x) sWl[i] = Wl[i];
    __syncthreads();
    int idx = blockIdx.x * blockDim.x + threadIdx.x;
    int stride = gridDim.x * blockDim.x;
    const float4* x4 = (const float4*)x;
    for (; idx < NN * HID; idx += stride) {
        int n = idx >> 6, c = idx & 63;
        float4 xv = x4[n];
        xl[idx] = xv.x * sWl[c] + xv.y * sWl[64 + c] + xv.z * sWl[128 + c] + xv.w * sWl[192 + c];
    }
}

// packed-math per-edge body; lrelu folded via lrelu(s)*a = s*(0.6a) + |s|*(0.4a).
// MASKED=0 -> no predicate (full window)
#define PROC1(L, IDX, MASKED)                                                 \
    {                                                                         \
        f32x2 L01 = {L.x, L.y}, L23 = {L.z, L.w};                             \
        f32x2 s01 = pk_add(L01, xr01);                                        \
        f32x2 s23 = pk_add(L23, xr23);                                        \
        f32x2 t01 = pk_abs(s01);                                              \
        f32x2 t23 = pk_abs(s23);                                              \
        f32x2 dd = pk_fma(s01, a06_01,                                        \
                   pk_fma(t01, a04_01,                                        \
                   pk_fma(s23, a06_23, pk_mul(t23, a04_23))));                \
        float vv = dd.x + dd.y;                                               \
        vv += __shfl_xor(vv, 1);                                              \
        vv += __shfl_xor(vv, 2);                                              \
        float ev = __expf(vv);                                                \
        if (MASKED && (IDX) >= cnt) ev = 0.f;                                 \
        ssum += ev;                                                           \
        f32x2 ev2 = {ev, ev};                                                 \
        ac01 = pk_fma(ev2, L01, ac01);                                        \
        ac23 = pk_fma(ev2, L23, ac23);                                        \
    }

// Fused GATv2 layer-1 pull: 1 wave per dst node; 16-edge full windows + 4-edge tail.
__global__ __launch_bounds__(256) void gather1_kernel(const int* __restrict__ rowptr,
                                                      const int* __restrict__ csr_src,
                                                      const float* __restrict__ x,
                                                      const float* __restrict__ Wr,
                                                      const float* __restrict__ att,
                                                      const float* __restrict__ xl,
                                                      const float* __restrict__ b1,
                                                      const float* __restrict__ g1,
                                                      const float* __restrict__ be1,
                                                      float* __restrict__ h) {
    __shared__ float sWr[4 * HID];
    __shared__ float satt[HID], sb[HID], sg[HID], sbe[HID];
    int tid = threadIdx.x;
    if (tid < 256) sWr[tid] = Wr[tid];
    if (tid < HID) {
        satt[tid] = att[tid];
        sb[tid] = b1[tid];
        sg[tid] = g1[tid];
        sbe[tid] = be1[tid];
    }
    __syncthreads();
    int node = blockIdx.x * 4 + (tid >> 6);
    if (node >= NN) return;
    int lane = tid & 63;
    int grp = lane >> 4;  // edge slot 0..3
    int ch = (lane & 15) * 4;
    int p0 = rowptr[node], p1 = rowptr[node + 1];

    float4 xd = *(const float4*)(x + node * 4);
    float xr0 = xd.x * sWr[ch + 0] + xd.y * sWr[64 + ch + 0] + xd.z * sWr[128 + ch + 0] + xd.w * sWr[192 + ch + 0];
    float xr1 = xd.x * sWr[ch + 1] + xd.y * sWr[64 + ch + 1] + xd.z * sWr[128 + ch + 1] + xd.w * sWr[192 + ch + 1];
    float xr2 = xd.x * sWr[ch + 2] + xd.y * sWr[64 + ch + 2] + xd.z * sWr[128 + ch + 2] + xd.w * sWr[192 + ch + 2];
    float xr3 = xd.x * sWr[ch + 3] + xd.y * sWr[64 + ch + 3] + xd.z * sWr[128 + ch + 3] + xd.w * sWr[192 + ch + 3];
    f32x2 xr01 = {xr0, xr1}, xr23 = {xr2, xr3};
    f32x2 a06_01 = {0.6f * satt[ch + 0], 0.6f * satt[ch + 1]};
    f32x2 a06_23 = {0.6f * satt[ch + 2], 0.6f * satt[ch + 3]};
    f32x2 a04_01 = {0.4f * satt[ch + 0], 0.4f * satt[ch + 1]};
    f32x2 a04_23 = {0.4f * satt[ch + 2], 0.4f * satt[ch + 3]};

    float ssum = 0.f;
    f32x2 ac01 = {0.f, 0.f}, ac23 = {0.f, 0.f};
    for (int p = p0; p < p1; p += 64) {
        int cnt = min(64, p1 - p);
        int srcs = (lane < cnt) ? csr_src[p + lane] : 0;
        int j = 0;
        for (; j + 16 <= cnt; j += 16) {
            int s0 = __shfl(srcs, j + grp);
            int s1 = __shfl(srcs, j + 4 + grp);
            int s2 = __shfl(srcs, j + 8 + grp);
            int s3 = __shfl(srcs, j + 12 + grp);
            float4 L0 = *(const float4*)(xl + (size_t)s0 * 64 + ch);
            float4 L1 = *(const float4*)(xl + (size_t)s1 * 64 + ch);
            float4 L2 = *(const float4*)(xl + (size_t)s2 * 64 + ch);
            float4 L3 = *(const float4*)(xl + (size_t)s3 * 64 + ch);
            PROC1(L0, 0, 0)
            PROC1(L1, 0, 0)
            PROC1(L2, 0, 0)
            PROC1(L3, 0, 0)
        }
        for (; j < cnt; j += 4) {
            int idx = j + grp;
            int s0 = __shfl(srcs, idx & 63);
            float4 L0 = *(const float4*)(xl + (size_t)s0 * 64 + ch);
            PROC1(L0, idx, 1)
        }
    }
    float ac0 = ac01.x, ac1 = ac01.y, ac2 = ac23.x, ac3 = ac23.y;
    ssum += __shfl_xor(ssum, 16);
    ac0 += __shfl_xor(ac0, 16); ac1 += __shfl_xor(ac1, 16);
    ac2 += __shfl_xor(ac2, 16); ac3 += __shfl_xor(ac3, 16);
    ssum += __shfl_xor(ssum, 32);
    ac0 += __shfl_xor(ac0, 32); ac1 += __shfl_xor(ac1, 32);
    ac2 += __shfl_xor(ac2, 32); ac3 += __shfl_xor(ac3, 32);
    float inv_s = (p1 > p0) ? __builtin_amdgcn_rcpf(ssum) : 0.f;
    float v0 = ac0 * inv_s + sb[ch + 0];
    float v1 = ac1 * inv_s + sb[ch + 1];
    float v2 = ac2 * inv_s + sb[ch + 2];
    float v3 = ac3 * inv_s + sb[ch + 3];
    float s4 = v0 + v1 + v2 + v3;
    s4 += __shfl_xor(s4, 1); s4 += __shfl_xor(s4, 2);
    s4 += __shfl_xor(s4, 4); s4 += __shfl_xor(s4, 8);
    float mu = s4 * (1.f / 64.f);
    float d0 = v0 - mu, d1 = v1 - mu, d2 = v2 - mu, d3 = v3 - mu;
    float q4 = d0 * d0 + d1 * d1 + d2 * d2 + d3 * d3;
    q4 += __shfl_xor(q4, 1); q4 += __shfl_xor(q4, 2);
    q4 += __shfl_xor(q4, 4); q4 += __shfl_xor(q4, 8);
    float inv = __builtin_amdgcn_rsqf(q4 * (1.f / 64.f) + 1e-5f);
    float y0 = d0 * inv * sg[ch + 0] + sbe[ch + 0];
    float y1 = d1 * inv * sg[ch + 1] + sbe[ch + 1];
    float y2 = d2 * inv * sg[ch + 2] + sbe[ch + 2];
    float y3 = d3 * inv * sg[ch + 3] + sbe[ch + 3];
    y0 = y0 > 0.f ? y0 : (__expf(y0) - 1.f);
    y1 = y1 > 0.f ? y1 : (__expf(y1) - 1.f);
    y2 = y2 > 0.f ? y2 : (__expf(y2) - 1.f);
    y3 = y3 > 0.f ? y3 : (__expf(y3) - 1.f);
    if (grp == 0) {
        float4 o = make_float4(y0, y1, y2, y3);
        *(float4*)(h + (size_t)node * 64 + ch) = o;
    }
}

// ---------- layer 2 ----------

__global__ __launch_bounds__(256) void lin2_kernel(const float* __restrict__ h,
                                                   const float* __restrict__ Wl,
                                                   const float* __restrict__ Wr,
                                                   float* __restrict__ xl2,
                                                   float* __restrict__ xr2) {
    __shared__ float sW[2 * HID * OUTC];
    __shared__ float sh[8 * HID];
    for (int i = threadIdx.x; i < HID * OUTC; i += blockDim.x) {
        sW[i] = Wl[i];
        sW[HID * OUTC + i] = Wr[i];
    }
    int node0 = blockIdx.x * 8;
    for (int i = threadIdx.x; i < 8 * HID; i += blockDim.x) {
        int n = node0 + (i >> 6);
        sh[i] = (n < NN) ? h[n * 64 + (i & 63)] : 0.f;
    }
    __syncthreads();
    int ln = threadIdx.x >> 5;
    int col = threadIdx.x & 31;
    int node = node0 + ln;
    if (node < NN) {
        float al = 0.f, ar = 0.f;
#pragma unroll
        for (int k = 0; k < HID; k++) {
            float hv = sh[ln * 64 + k];
            al += hv * sW[k * 32 + col];
            ar += hv * sW[HID * OUTC + k * 32 + col];
        }
        xl2[node * 32 + col] = al;
        xr2[node * 32 + col] = ar;
    }
}

#define PROC2(L, IDX, MASKED)                                                 \
    {                                                                         \
        f32x2 L01 = {L.x, L.y}, L23 = {L.z, L.w};                             \
        f32x2 s01 = pk_add(L01, xr01);                                        \
        f32x2 s23 = pk_add(L23, xr23);                                        \
        f32x2 t01 = pk_abs(s01);                                              \
        f32x2 t23 = pk_abs(s23);                                              \
        f32x2 dd = pk_fma(s01, a06_01,                                        \
                   pk_fma(t01, a04_01,                                        \
                   pk_fma(s23, a06_23, pk_mul(t23, a04_23))));                \
        float vv = dd.x + dd.y;                                               \
        vv += __shfl_xor(vv, 1);                                              \
        vv += __shfl_xor(vv, 2);                                              \
        vv += __shfl_xor(vv, 4);                                              \
        float ev = __expf(vv);                                                \
        if (MASKED && (IDX) >= cnt) ev = 0.f;                                 \
        ssum += ev;                                                           \
        f32x2 ev2 = {ev, ev};                                                 \
        ac01 = pk_fma(ev2, L01, ac01);                                        \
        ac23 = pk_fma(ev2, L23, ac23);                                        \
    }

// Fused GATv2 layer-2 pull: 1 wave per dst node; 16-edge full windows + 8-edge tail.
__global__ __launch_bounds__(256) void gather2_kernel(const int* __restrict__ rowptr,
                                                      const int* __restrict__ csr_src,
                                                      const float* __restrict__ xl2,
                                                      const float* __restrict__ xr2v,
                                                      const float* __restrict__ att,
                                                      const float* __restrict__ b2,
                                                      const float* __restrict__ g2,
                                                      const float* __restrict__ be2,
                                                      float* __restrict__ out) {
    __shared__ float satt[OUTC], sb[OUTC], sg[OUTC], sbe[OUTC];
    int tid = threadIdx.x;
    if (tid < OUTC) {
        satt[tid] = att[tid];
        sb[tid] = b2[tid];
        sg[tid] = g2[tid];
        sbe[tid] = be2[tid];
    }
    __syncthreads();
    int node = blockIdx.x * 4 + (tid >> 6);
    if (node >= NN) return;
    int lane = tid & 63;
    int grp = lane >> 3;  // edge slot 0..7
    int ch = (lane & 7) * 4;
    int p0 = rowptr[node], p1 = rowptr[node + 1];

    float4 xr = *(const float4*)(xr2v + (size_t)node * 32 + ch);
    f32x2 xr01 = {xr.x, xr.y}, xr23 = {xr.z, xr.w};
    f32x2 a06_01 = {0.6f * satt[ch + 0], 0.6f * satt[ch + 1]};
    f32x2 a06_23 = {0.6f * satt[ch + 2], 0.6f * satt[ch + 3]};
    f32x2 a04_01 = {0.4f * satt[ch + 0], 0.4f * satt[ch + 1]};
    f32x2 a04_23 = {0.4f * satt[ch + 2], 0.4f * satt[ch + 3]};

    float ssum = 0.f;
    f32x2 ac01 = {0.f, 0.f}, ac23 = {0.f, 0.f};
    for (int p = p0; p < p1; p += 64) {
        int cnt = min(64, p1 - p);
        int srcs = (lane < cnt) ? csr_src[p + lane] : 0;
        int j = 0;
        for (; j + 16 <= cnt; j += 16) {
            int s0 = __shfl(srcs, j + grp);
            int s1 = __shfl(srcs, j + 8 + grp);
            float4 L0 = *(const float4*)(xl2 + (size_t)s0 * 32 + ch);
            float4 L1 = *(const float4*)(xl2 + (size_t)s1 * 32 + ch);
            PROC2(L0, 0, 0)
            PROC2(L1, 0, 0)
        }
        for (; j < cnt; j += 8) {
            int idx = j + grp;
            int s0 = __shfl(srcs, idx & 63);
            float4 L0 = *(const float4*)(xl2 + (size_t)s0 * 32 + ch);
            PROC2(L0, idx, 1)
        }
    }
    float ac0 = ac01.x, ac1 = ac01.y, ac2 = ac23.x, ac3 = ac23.y;
    for (int off = 8; off < 64; off <<= 1) {
        ssum += __shfl_xor(ssum, off);
        ac0 += __shfl_xor(ac0, off); ac1 += __shfl_xor(ac1, off);
        ac2 += __shfl_xor(ac2, off); ac3 += __shfl_xor(ac3, off);
    }
    float inv_s = (p1 > p0) ? __builtin_amdgcn_rcpf(ssum) : 0.f;
    float v0 = ac0 * inv_s + sb[ch + 0];
    float v1 = ac1 * inv_s + sb[ch + 1];
    float v2 = ac2 * inv_s + sb[ch + 2];
    float v3 = ac3 * inv_s + sb[ch + 3];
    float s4 = v0 + v1 + v2 + v3;
    s4 += __shfl_xor(s4, 1); s4 += __shfl_xor(s4, 2); s4 += __shfl_xor(s4, 4);
    float mu = s4 * (1.f / 32.f);
    float d0 = v0 - mu, d1 = v1 - mu, d2 = v2 - mu, d3 = v3 - mu;
    float q4 = d0 * d0 + d1 * d1 + d2 * d2 + d3 * d3;
    q4 += __shfl_xor(q4, 1); q4 += __shfl_xor(q4, 2); q4 += __shfl_xor(q4, 4);
    float inv = __builtin_amdgcn_rsqf(q4 * (1.f / 32.f) + 1e-5f);
    if (grp == 0) {
        float4 o;
        o.x = d0 * inv * sg[ch + 0] + sbe[ch + 0];
        o.y = d1 * inv * sg[ch + 1] + sbe[ch + 1];
        o.z = d2 * inv * sg[ch + 2] + sbe[ch + 2];
        o.w = d3 * inv * sg[ch + 3] + sbe[ch + 3];
        *(float4*)(out + (size_t)node * 32 + ch) = o;
    }
}

extern "C" void kernel_launch(void* const* d_in, const int* in_sizes, int n_in,
                              void* d_out, int out_size, void* d_ws, size_t ws_size,
                              hipStream_t stream) {
    const float* x    = (const float*)d_in[0];
    const int* ei     = (const int*)d_in[1];
    const float* Wl1  = (const float*)d_in[2];
    const float* Wr1  = (const float*)d_in[3];
    const float* att1 = (const float*)d_in[4];
    const float* b1   = (const float*)d_in[5];
    const float* g1   = (const float*)d_in[6];
    const float* be1  = (const float*)d_in[7];
    const float* Wl2  = (const float*)d_in[8];
    const float* Wr2  = (const float*)d_in[9];
    const float* att2 = (const float*)d_in[10];
    const float* b2   = (const float*)d_in[11];
    const float* g2   = (const float*)d_in[12];
    const float* be2  = (const float*)d_in[13];
    float* out = (float*)d_out;

    float* ws = (float*)d_ws;
    float* xl1 = ws;                               // N*64; reused as xl2/xr2
    float* xl2 = xl1;
    float* xr2 = xl1 + (size_t)NN * 32;
    float* h = xl1 + (size_t)NN * 64;              // N*64
    int* rowptr = (int*)(h + (size_t)NN * 64);     // N+1
    int* csr_src = rowptr + NN + 1;                // E
    unsigned int* staging = (unsigned int*)(csr_src + NE);  // E
    int* gcount = (int*)(staging + NE);            // NBUCK
    int* gbase = gcount + NBUCK;                   // NBUCK+1
    int* blkcnt = gbase + NBUCK + 1;               // NBUCK*NPB
    int* cursors = blkcnt + NBUCK * NPB;           // NBUCK*NPB

    const int B = 256;

    // ---- CSR build: bucket sort (shared by both layers) ----
    hipMemsetAsync(gcount, 0, NBUCK * sizeof(int), stream);
    bucketA_kernel<<<NPB, B, 0, stream>>>(ei, gcount, blkcnt);
    scanBlk_kernel<<<NBUCK, B, 0, stream>>>(gcount, blkcnt, cursors, gbase);
    bucketB_kernel<<<NPB, B, 0, stream>>>(ei, cursors, staging);
    bucketC_kernel<<<NBUCK, B, 0, stream>>>(staging, gbase, rowptr, csr_src);

    // ---- layer 1 ----
    lin1_kernel<<<(NN * 64 + B - 1) / B, B, 0, stream>>>(x, Wl1, xl1);
    gather1_kernel<<<(NN + 3) / 4, B, 0, stream>>>(rowptr, csr_src, x, Wr1, att1, xl1,
                                                   b1, g1, be1, h);

    // ---- layer 2 ----
    lin2_kernel<<<(NN + 7) / 8, B, 0, stream>>>(h, Wl2, Wr2, xl2, xr2);
    gather2_kernel<<<(NN + 3) / 4, B, 0, stream>>>(rowptr, csr_src, xl2, xr2, att2,
                                                   b2, g2, be2, out);
}